// Round 12
// baseline (732.481 us; speedup 1.0000x reference)
//
#include <hip/hip_runtime.h>

#define TSEQ 512
#define NTH  512    // 8 waves: 0-3 layer0, 4-7 layer1 (skew 2)
#define BT   8      // batch per block; 512 blocks = 2 blocks/CU -> 4 waves/SIMD
// R12: occupancy 2x via BT=8 + 512 blocks. MFMA cols 8-15 = duplicates of 0-7
// (x loaded at rl&7; dup lanes maintain dup h in plane rows 8-15). Per-CU VALU
// work unchanged, MFMA issue x2 (was only 24% busy), idle hidden by 2 blocks'
// independent barrier domains interleaving on each SIMD.

typedef __attribute__((ext_vector_type(8))) _Float16 half8;
typedef __attribute__((ext_vector_type(4))) float f32x4;
typedef __attribute__((ext_vector_type(4))) unsigned int u32x4;

// pack two f32 into one f16-RNE pair word
__device__ __forceinline__ unsigned packF16x2(float a, float b) {
    _Float16 ha = (_Float16)a, hb = (_Float16)b;
    unsigned short ua = __builtin_bit_cast(unsigned short, ha);
    unsigned short ub = __builtin_bit_cast(unsigned short, hb);
    return (unsigned)ua | ((unsigned)ub << 16);
}
// 8 f32 weights -> f16x8 A-fragment (element e <-> k-offset e)
__device__ __forceinline__ half8 packA16(const float w8[8]) {
    u32x4 W = { packF16x2(w8[0], w8[1]), packF16x2(w8[2], w8[3]),
                packF16x2(w8[4], w8[5]), packF16x2(w8[6], w8[7]) };
    return __builtin_bit_cast(half8, W);
}

#define MFMA(a, b, c) __builtin_amdgcn_mfma_f32_16x16x32_f16((a), (b), (c), 0, 0, 0)
#define LD128H(p) __builtin_bit_cast(half8, *(const u32x4*)(p))

// fused LSTM unit update: 5 exp2 + 3 rcp
__device__ __forceinline__ float act_fused(float ai, float af, float ag, float ao, float* c) {
    const float L2E = 1.44269504088896340736f;
    float ei = __builtin_amdgcn_exp2f(-ai * L2E);
    float ef = __builtin_amdgcn_exp2f(-af * L2E);
    float eg = __builtin_amdgcn_exp2f(2.0f * L2E * ag);
    float eo = __builtin_amdgcn_exp2f(-ao * L2E);
    float sf = __builtin_amdgcn_rcpf(1.0f + ef);
    float ig = (eg - 1.0f) * __builtin_amdgcn_rcpf((1.0f + ei) * (eg + 1.0f));
    float cn = fmaf(*c, sf, ig);
    *c = cn;
    float ec = __builtin_amdgcn_exp2f(2.0f * L2E * cn);
    return (ec - 1.0f) * __builtin_amdgcn_rcpf((1.0f + eo) * (ec + 1.0f));
}

__global__ __launch_bounds__(NTH, 4)
void lstm2_mfma(const float* __restrict__ x,
                const float* __restrict__ W_ih0, const float* __restrict__ W_hh0,
                const float* __restrict__ b_ih0, const float* __restrict__ b_hh0,
                const float* __restrict__ W_ih1, const float* __restrict__ W_hh1,
                const float* __restrict__ b_ih1, const float* __restrict__ b_hh1,
                const float* __restrict__ W_fc,  const float* __restrict__ b_fc,
                float* __restrict__ out)
{
    const int tid  = threadIdx.x;
    const int lane = tid & 63;
    const int wv   = tid >> 6;        // 0-3: layer0, 4-7: layer1
    const int rl   = lane & 15;       // MFMA row/col index; batch col n = rl&7 (8-15 dup)
    const int g    = lane >> 4;       // k-group 0..3
    const int b0   = blockIdx.x * BT;

    // f16 h planes (2 units/word), depth-2 ping-pong, compile-time bases.
    // h[t] lives at parity (t+1)&1. Rows 8-15 hold duplicates of rows 0-7.
    __shared__ unsigned h0P0[512], h0P1[512];
    __shared__ unsigned h1P0[512], h1P1[512];
    __shared__ float fcl[64 * 17];    // padded 16->17

    for (int i2 = tid; i2 < 512; i2 += NTH) {
        h0P0[i2] = 0u; h0P1[i2] = 0u; h1P0[i2] = 0u; h1P1[i2] = 0u;
    }
    __syncthreads();

    // diagonal-swizzle b128 read offsets (loop-invariant)
    const int offL = rl*32 + (((g + rl) & 7) << 2);         // k-half 0
    const int offH = rl*32 + (((4 + g + rl) & 7) << 2);     // k-half 1
    const int q0w  = 8*((wv & 3)) + 2*g;
    const int woff = rl*32 + ((((q0w >> 2) + rl) & 7) << 2) + (q0w & 3);

    if (wv < 4) {
        // ======== LAYER 0: wave w owns u in [16w,16w+16) for all 4 gates ========
        const int w = wv;
        half8 A0[4][2];   // [gate][k-half of W_hh0]
        half8 Ax[4];      // x-term: k0-3 = W_ih0 row (g==0 lanes), else 0
        f32x4 bias4[4];
        #pragma unroll
        for (int G = 0; G < 4; ++G) {
            const int row = 64*G + 16*w + rl;
            #pragma unroll
            for (int s = 0; s < 2; ++s) {
                float w8[8];
                const float* src = W_hh0 + row*64 + s*32 + g*8;
                #pragma unroll
                for (int e = 0; e < 8; ++e) w8[e] = src[e];
                A0[G][s] = packA16(w8);
            }
            {
                u32x4 ax = {0u, 0u, 0u, 0u};
                if (g == 0) {
                    ax.x = packF16x2(W_ih0[row*4+0], W_ih0[row*4+1]);
                    ax.y = packF16x2(W_ih0[row*4+2], W_ih0[row*4+3]);
                }
                Ax[G] = __builtin_bit_cast(half8, ax);
            }
            const int rb = 64*G + 16*w + 4*g;
            bias4[G].x = b_ih0[rb+0] + b_hh0[rb+0];
            bias4[G].y = b_ih0[rb+1] + b_hh0[rb+1];
            bias4[G].z = b_ih0[rb+2] + b_hh0[rb+2];
            bias4[G].w = b_ih0[rb+3] + b_hh0[rb+3];
        }
        float cst[4] = {0.f, 0.f, 0.f, 0.f};

        // x[t] register-prefetched; lane loads batch col rl&7 (cols 8-15 duplicate)
        f32x4 xcur = *(const f32x4*)(x + ((size_t)(b0 + (rl & 7)) * TSEQ) * 4);

        auto body0 = [&](const unsigned* rP, unsigned* wP, int i) {
            // h0[t-1] B-frags (f16 single plane)
            half8 B0 = LD128H(rP + offL);
            half8 B1 = LD128H(rP + offH);
            // x B-frag built in-lane from registers (k0-3 = x f16, g==0 lanes)
            u32x4 tx = {0u, 0u, 0u, 0u};
            if (g == 0) {
                tx.x = packF16x2(xcur.x, xcur.y);
                tx.y = packF16x2(xcur.z, xcur.w);
            }
            half8 Bx = __builtin_bit_cast(half8, tx);

            f32x4 acc[4];
            __builtin_amdgcn_s_setprio(1);
            // x-group first: register-only operands, no LDS wait
            #pragma unroll
            for (int G = 0; G < 4; ++G) acc[G] = MFMA(Ax[G], Bx, bias4[G]);
            #pragma unroll
            for (int G = 0; G < 4; ++G) acc[G] = MFMA(A0[G][0], B0, acc[G]);
            #pragma unroll
            for (int G = 0; G < 4; ++G) acc[G] = MFMA(A0[G][1], B1, acc[G]);
            __builtin_amdgcn_s_setprio(0);

            float hv[4];
            #pragma unroll
            for (int j = 0; j < 4; ++j)
                hv[j] = act_fused(acc[0][j], acc[1][j], acc[2][j], acc[3][j], &cst[j]);
            *(uint2*)(wP + woff) = make_uint2(packF16x2(hv[0], hv[1]),
                                              packF16x2(hv[2], hv[3]));

            if (i + 1 < TSEQ)
                xcur = *(const f32x4*)(x + ((size_t)(b0 + (rl & 7)) * TSEQ + (i + 1)) * 4);
        };

        for (int ii = 0; ii < 256; ++ii) {
            body0(h0P0, h0P1, 2*ii);     __syncthreads();  // i=2ii   (p=0)
            body0(h0P1, h0P0, 2*ii + 1); __syncthreads();  // i=2ii+1 (p=1)
        }
        __syncthreads();   // i=512 slot (L1 tail)
        __syncthreads();   // i=513 slot (L1 tail)
    } else {
        // ======== LAYER 1 (skew 2): iter i computes t=i-2; h0 frags prefetched at i-1 ====
        const int w = wv - 4;
        half8 A1[4][4];   // s=0,1: W_ih1 (vs h0); s=2,3: W_hh1 (vs h1)
        f32x4 bias4[4];
        #pragma unroll
        for (int G = 0; G < 4; ++G) {
            const int row = 64*G + 16*w + rl;
            #pragma unroll
            for (int s = 0; s < 4; ++s) {
                float w8[8];
                const float* src = (s < 2) ? (W_ih1 + row*64 + s*32 + g*8)
                                           : (W_hh1 + row*64 + (s-2)*32 + g*8);
                #pragma unroll
                for (int e = 0; e < 8; ++e) w8[e] = src[e];
                A1[G][s] = packA16(w8);
            }
            const int rb = 64*G + 16*w + 4*g;
            bias4[G].x = b_ih1[rb+0] + b_hh1[rb+0];
            bias4[G].y = b_ih1[rb+1] + b_hh1[rb+1];
            bias4[G].z = b_ih1[rb+2] + b_hh1[rb+2];
            bias4[G].w = b_ih1[rb+3] + b_hh1[rb+3];
        }
        float cst[4] = {0.f, 0.f, 0.f, 0.f};
        const int u0 = 16*w + 4*g;

        half8 pB0 = {}, pB1 = {};   // prefetched h0[t] frags

        auto body1 = [&](const unsigned* r1P,               // h1[t-1] read plane (p)
                         unsigned* wP,                      // h1[t] write plane (p^1)
                         const unsigned* n0P,               // h0 prefetch plane (p)
                         bool wrFC) {
            // h1 reads issue at top; consumed 2 MFMA-groups later (latency hidden)
            half8 B2 = LD128H(r1P + offL);
            half8 B3 = LD128H(r1P + offH);

            f32x4 acc[4];
            __builtin_amdgcn_s_setprio(1);
            // s=0,1 on prefetched h0 frags: start immediately after barrier
            #pragma unroll
            for (int G = 0; G < 4; ++G) acc[G] = MFMA(A1[G][0], pB0, bias4[G]);
            #pragma unroll
            for (int G = 0; G < 4; ++G) acc[G] = MFMA(A1[G][1], pB1, acc[G]);
            // s=2,3 on just-read h1 frags
            #pragma unroll
            for (int G = 0; G < 4; ++G) acc[G] = MFMA(A1[G][2], B2, acc[G]);
            #pragma unroll
            for (int G = 0; G < 4; ++G) acc[G] = MFMA(A1[G][3], B3, acc[G]);
            __builtin_amdgcn_s_setprio(0);

            // prefetch h0[t+1] now: latency hides under act+pack+write
            pB0 = LD128H(n0P + offL);
            pB1 = LD128H(n0P + offH);

            float hv[4];
            #pragma unroll
            for (int j = 0; j < 4; ++j)
                hv[j] = act_fused(acc[0][j], acc[1][j], acc[2][j], acc[3][j], &cst[j]);
            *(uint2*)(wP + woff) = make_uint2(packF16x2(hv[0], hv[1]),
                                              packF16x2(hv[2], hv[3]));
            if (wrFC) {
                #pragma unroll
                for (int j = 0; j < 4; ++j) fcl[(u0 + j)*17 + rl] = hv[j];
            }
        };

        __syncthreads();                         // i=0 (idle)
        // i=1: prefetch-only — h0[0] lives at parity 1
        pB0 = LD128H(h0P1 + offL);
        pB1 = LD128H(h0P1 + offH);
        __syncthreads();                         // i=1
        for (int ii = 0; ii < 256; ++ii) {
            // i=2+2ii (p=0): read h1@P0, write@P1, prefetch h0@P0
            body1(h1P0, h1P1, h0P0, false);     __syncthreads();
            // i=3+2ii (p=1): read h1@P1, write@P0, prefetch h0@P1; last (i=513) writes FC
            body1(h1P1, h1P0, h0P1, ii == 255); __syncthreads();
        }
    }

    // ---- FC: out[b] = h1_last[b,:] . W_fc + b_fc ----
    if (tid < BT) {
        float acc = b_fc[0];
        #pragma unroll 16
        for (int u = 0; u < 64; ++u) acc += fcl[u*17 + tid] * W_fc[u];
        out[b0 + tid] = acc;
    }
}

extern "C" void kernel_launch(void* const* d_in, const int* in_sizes, int n_in,
                              void* d_out, int out_size, void* d_ws, size_t ws_size,
                              hipStream_t stream) {
    const float* x     = (const float*)d_in[0];
    const float* W_ih0 = (const float*)d_in[1];
    const float* W_hh0 = (const float*)d_in[2];
    const float* b_ih0 = (const float*)d_in[3];
    const float* b_hh0 = (const float*)d_in[4];
    const float* W_ih1 = (const float*)d_in[5];
    const float* W_hh1 = (const float*)d_in[6];
    const float* b_ih1 = (const float*)d_in[7];
    const float* b_hh1 = (const float*)d_in[8];
    const float* W_fc  = (const float*)d_in[9];
    const float* b_fc  = (const float*)d_in[10];
    float* out = (float*)d_out;

    dim3 grid(4096 / BT), block(NTH);
    hipLaunchKernelGGL(lstm2_mfma, grid, block, 0, stream,
                       x, W_ih0, W_hh0, b_ih0, b_hh0,
                       W_ih1, W_hh1, b_ih1, b_hh1, W_fc, b_fc, out);
}

// Round 13
// 341.686 us; speedup vs baseline: 2.1437x; 2.1437x over previous
//
#include <hip/hip_runtime.h>

#define TSEQ 512
#define NTH  512    // 8 waves: 0-3 layer0, 4-7 layer1 (skew 2); 16 batch/block, 256 blocks = 1/CU
// R13 (from best=R11): (1) x-load hoisted to body top so the pre-barrier
// vmcnt(0) drain no longer stalls every step on a fresh global load;
// (2) activation log2e scale factors folded into weights/biases at init
// (i,f,o rows * -log2e; g rows * 2*log2e) -> 4 fewer v_mul per unit;
// (3) launch_bounds(512,1): free VGPR headroom (grid=256 -> 1 block/CU anyway).

typedef __attribute__((ext_vector_type(8))) _Float16 half8;
typedef __attribute__((ext_vector_type(4))) float f32x4;
typedef __attribute__((ext_vector_type(4))) unsigned int u32x4;

// pack two f32 into one f16-RNE pair word
__device__ __forceinline__ unsigned packF16x2(float a, float b) {
    _Float16 ha = (_Float16)a, hb = (_Float16)b;
    unsigned short ua = __builtin_bit_cast(unsigned short, ha);
    unsigned short ub = __builtin_bit_cast(unsigned short, hb);
    return (unsigned)ua | ((unsigned)ub << 16);
}
// 8 f32 weights (pre-scaled by s) -> f16x8 A-fragment (element e <-> k-offset e)
__device__ __forceinline__ half8 packA16s(const float w8[8], float s) {
    u32x4 W = { packF16x2(w8[0]*s, w8[1]*s), packF16x2(w8[2]*s, w8[3]*s),
                packF16x2(w8[4]*s, w8[5]*s), packF16x2(w8[6]*s, w8[7]*s) };
    return __builtin_bit_cast(half8, W);
}

#define MFMA(a, b, c) __builtin_amdgcn_mfma_f32_16x16x32_f16((a), (b), (c), 0, 0, 0)
#define LD128H(p) __builtin_bit_cast(half8, *(const u32x4*)(p))

// fused LSTM unit update with PRE-SCALED pre-acts:
// ai,af,ao = -log2e * (true preact);  ag = 2*log2e * (true preact)
__device__ __forceinline__ float act_fused(float ai, float af, float ag, float ao, float* c) {
    const float L2E2 = 2.88539008177792681472f;   // 2*log2(e)
    float ei = __builtin_amdgcn_exp2f(ai);
    float ef = __builtin_amdgcn_exp2f(af);
    float eg = __builtin_amdgcn_exp2f(ag);
    float eo = __builtin_amdgcn_exp2f(ao);
    float sf = __builtin_amdgcn_rcpf(1.0f + ef);
    float ig = (eg - 1.0f) * __builtin_amdgcn_rcpf((1.0f + ei) * (eg + 1.0f));
    float cn = fmaf(*c, sf, ig);
    *c = cn;
    float ec = __builtin_amdgcn_exp2f(cn * L2E2);
    return (ec - 1.0f) * __builtin_amdgcn_rcpf((1.0f + eo) * (ec + 1.0f));
}

__global__ __launch_bounds__(NTH, 1)
void lstm2_mfma(const float* __restrict__ x,
                const float* __restrict__ W_ih0, const float* __restrict__ W_hh0,
                const float* __restrict__ b_ih0, const float* __restrict__ b_hh0,
                const float* __restrict__ W_ih1, const float* __restrict__ W_hh1,
                const float* __restrict__ b_ih1, const float* __restrict__ b_hh1,
                const float* __restrict__ W_fc,  const float* __restrict__ b_fc,
                float* __restrict__ out)
{
    const int tid  = threadIdx.x;
    const int lane = tid & 63;
    const int wv   = tid >> 6;        // 0-3: layer0, 4-7: layer1
    const int rl   = lane & 15;       // MFMA row/col index = batch col n
    const int g    = lane >> 4;       // k-group 0..3
    const int b0   = blockIdx.x * 16;

    const float NL2E = -1.44269504088896340736f;  // gate i,f,o row scale
    const float PL2E2 = 2.88539008177792681472f;  // gate g row scale

    // f16 h planes (2 units/word), depth-2 ping-pong, compile-time bases.
    // h[t] lives at parity (t+1)&1.
    __shared__ unsigned h0P0[512], h0P1[512];
    __shared__ unsigned h1P0[512], h1P1[512];
    __shared__ float fcl[64 * 17];    // padded 16->17

    for (int i2 = tid; i2 < 512; i2 += NTH) {
        h0P0[i2] = 0u; h0P1[i2] = 0u; h1P0[i2] = 0u; h1P1[i2] = 0u;
    }
    __syncthreads();

    // diagonal-swizzle b128 read offsets (loop-invariant)
    const int offL = rl*32 + (((g + rl) & 7) << 2);         // k-half 0
    const int offH = rl*32 + (((4 + g + rl) & 7) << 2);     // k-half 1
    const int q0w  = 8*((wv & 3)) + 2*g;
    const int woff = rl*32 + ((((q0w >> 2) + rl) & 7) << 2) + (q0w & 3);

    if (wv < 4) {
        // ======== LAYER 0: wave w owns u in [16w,16w+16) for all 4 gates ========
        const int w = wv;
        half8 A0[4][2];   // [gate][k-half of W_hh0]
        half8 Ax[4];      // x-term: k0-3 = W_ih0 row (g==0 lanes), else 0
        f32x4 bias4[4];
        #pragma unroll
        for (int G = 0; G < 4; ++G) {
            const float sc = (G == 2) ? PL2E2 : NL2E;
            const int row = 64*G + 16*w + rl;
            #pragma unroll
            for (int s = 0; s < 2; ++s) {
                float w8[8];
                const float* src = W_hh0 + row*64 + s*32 + g*8;
                #pragma unroll
                for (int e = 0; e < 8; ++e) w8[e] = src[e];
                A0[G][s] = packA16s(w8, sc);
            }
            {
                u32x4 ax = {0u, 0u, 0u, 0u};
                if (g == 0) {
                    ax.x = packF16x2(W_ih0[row*4+0]*sc, W_ih0[row*4+1]*sc);
                    ax.y = packF16x2(W_ih0[row*4+2]*sc, W_ih0[row*4+3]*sc);
                }
                Ax[G] = __builtin_bit_cast(half8, ax);
            }
            const int rb = 64*G + 16*w + 4*g;
            bias4[G].x = (b_ih0[rb+0] + b_hh0[rb+0]) * sc;
            bias4[G].y = (b_ih0[rb+1] + b_hh0[rb+1]) * sc;
            bias4[G].z = (b_ih0[rb+2] + b_hh0[rb+2]) * sc;
            bias4[G].w = (b_ih0[rb+3] + b_hh0[rb+3]) * sc;
        }
        float cst[4] = {0.f, 0.f, 0.f, 0.f};

        // prologue: load x[0] and pre-pack its B-frag words
        f32x4 xf = *(const f32x4*)(x + ((size_t)(b0 + rl) * TSEQ) * 4);
        unsigned bx0 = packF16x2(xf.x, xf.y);
        unsigned bx1 = packF16x2(xf.z, xf.w);

        auto body0 = [&](const unsigned* rP, unsigned* wP, int i) {
            // issue x[t+1] load FIRST: ~full body hides its latency; consumed at pack below
            if (i + 1 < TSEQ)
                xf = *(const f32x4*)(x + ((size_t)(b0 + rl) * TSEQ + (i + 1)) * 4);

            // h0[t-1] B-frags (f16 single plane)
            half8 B0 = LD128H(rP + offL);
            half8 B1 = LD128H(rP + offH);
            // x B-frag from pre-packed words (packed during previous interval)
            u32x4 tx = {0u, 0u, 0u, 0u};
            if (g == 0) { tx.x = bx0; tx.y = bx1; }
            half8 Bx = __builtin_bit_cast(half8, tx);

            f32x4 acc[4];
            __builtin_amdgcn_s_setprio(1);
            // x-group first: register-only operands, no LDS wait
            #pragma unroll
            for (int G = 0; G < 4; ++G) acc[G] = MFMA(Ax[G], Bx, bias4[G]);
            #pragma unroll
            for (int G = 0; G < 4; ++G) acc[G] = MFMA(A0[G][0], B0, acc[G]);
            #pragma unroll
            for (int G = 0; G < 4; ++G) acc[G] = MFMA(A0[G][1], B1, acc[G]);
            __builtin_amdgcn_s_setprio(0);

            float hv[4];
            #pragma unroll
            for (int j = 0; j < 4; ++j)
                hv[j] = act_fused(acc[0][j], acc[1][j], acc[2][j], acc[3][j], &cst[j]);

            // pack x[t+1] B-frag now (load issued at body top has completed by here)
            bx0 = packF16x2(xf.x, xf.y);
            bx1 = packF16x2(xf.z, xf.w);

            *(uint2*)(wP + woff) = make_uint2(packF16x2(hv[0], hv[1]),
                                              packF16x2(hv[2], hv[3]));
        };

        for (int ii = 0; ii < 256; ++ii) {
            body0(h0P0, h0P1, 2*ii);     __syncthreads();  // i=2ii   (p=0)
            body0(h0P1, h0P0, 2*ii + 1); __syncthreads();  // i=2ii+1 (p=1)
        }
        __syncthreads();   // i=512 slot (L1 tail)
        __syncthreads();   // i=513 slot (L1 tail)
    } else {
        // ======== LAYER 1 (skew 2): iter i computes t=i-2; h0 frags prefetched at i-1 ====
        const int w = wv - 4;
        half8 A1[4][4];   // s=0,1: W_ih1 (vs h0); s=2,3: W_hh1 (vs h1)
        f32x4 bias4[4];
        #pragma unroll
        for (int G = 0; G < 4; ++G) {
            const float sc = (G == 2) ? PL2E2 : NL2E;
            const int row = 64*G + 16*w + rl;
            #pragma unroll
            for (int s = 0; s < 4; ++s) {
                float w8[8];
                const float* src = (s < 2) ? (W_ih1 + row*64 + s*32 + g*8)
                                           : (W_hh1 + row*64 + (s-2)*32 + g*8);
                #pragma unroll
                for (int e = 0; e < 8; ++e) w8[e] = src[e];
                A1[G][s] = packA16s(w8, sc);
            }
            const int rb = 64*G + 16*w + 4*g;
            bias4[G].x = (b_ih1[rb+0] + b_hh1[rb+0]) * sc;
            bias4[G].y = (b_ih1[rb+1] + b_hh1[rb+1]) * sc;
            bias4[G].z = (b_ih1[rb+2] + b_hh1[rb+2]) * sc;
            bias4[G].w = (b_ih1[rb+3] + b_hh1[rb+3]) * sc;
        }
        float cst[4] = {0.f, 0.f, 0.f, 0.f};
        const int u0 = 16*w + 4*g;

        half8 pB0 = {}, pB1 = {};   // prefetched h0[t] frags

        auto body1 = [&](const unsigned* r1P,               // h1[t-1] read plane (p)
                         unsigned* wP,                      // h1[t] write plane (p^1)
                         const unsigned* n0P,               // h0 prefetch plane (p)
                         bool wrFC) {
            // h1 reads issue at top; consumed 2 MFMA-groups later (latency hidden)
            half8 B2 = LD128H(r1P + offL);
            half8 B3 = LD128H(r1P + offH);

            f32x4 acc[4];
            __builtin_amdgcn_s_setprio(1);
            // s=0,1 on prefetched h0 frags: start immediately after barrier
            #pragma unroll
            for (int G = 0; G < 4; ++G) acc[G] = MFMA(A1[G][0], pB0, bias4[G]);
            #pragma unroll
            for (int G = 0; G < 4; ++G) acc[G] = MFMA(A1[G][1], pB1, acc[G]);
            // s=2,3 on just-read h1 frags
            #pragma unroll
            for (int G = 0; G < 4; ++G) acc[G] = MFMA(A1[G][2], B2, acc[G]);
            #pragma unroll
            for (int G = 0; G < 4; ++G) acc[G] = MFMA(A1[G][3], B3, acc[G]);
            __builtin_amdgcn_s_setprio(0);

            // prefetch h0[t+1] now: latency hides under act+pack+write
            pB0 = LD128H(n0P + offL);
            pB1 = LD128H(n0P + offH);

            float hv[4];
            #pragma unroll
            for (int j = 0; j < 4; ++j)
                hv[j] = act_fused(acc[0][j], acc[1][j], acc[2][j], acc[3][j], &cst[j]);
            *(uint2*)(wP + woff) = make_uint2(packF16x2(hv[0], hv[1]),
                                              packF16x2(hv[2], hv[3]));
            if (wrFC) {
                #pragma unroll
                for (int j = 0; j < 4; ++j) fcl[(u0 + j)*17 + rl] = hv[j];
            }
        };

        __syncthreads();                         // i=0 (idle)
        // i=1: prefetch-only — h0[0] lives at parity 1
        pB0 = LD128H(h0P1 + offL);
        pB1 = LD128H(h0P1 + offH);
        __syncthreads();                         // i=1
        for (int ii = 0; ii < 256; ++ii) {
            // i=2+2ii (p=0): read h1@P0, write@P1, prefetch h0@P0
            body1(h1P0, h1P1, h0P0, false);     __syncthreads();
            // i=3+2ii (p=1): read h1@P1, write@P0, prefetch h0@P1; last (i=513) writes FC
            body1(h1P1, h1P0, h0P1, ii == 255); __syncthreads();
        }
    }

    // ---- FC: out[b] = h1_last[b,:] . W_fc + b_fc ----
    if (tid < 16) {
        float acc = b_fc[0];
        #pragma unroll 16
        for (int u = 0; u < 64; ++u) acc += fcl[u*17 + tid] * W_fc[u];
        out[b0 + tid] = acc;
    }
}

extern "C" void kernel_launch(void* const* d_in, const int* in_sizes, int n_in,
                              void* d_out, int out_size, void* d_ws, size_t ws_size,
                              hipStream_t stream) {
    const float* x     = (const float*)d_in[0];
    const float* W_ih0 = (const float*)d_in[1];
    const float* W_hh0 = (const float*)d_in[2];
    const float* b_ih0 = (const float*)d_in[3];
    const float* b_hh0 = (const float*)d_in[4];
    const float* W_ih1 = (const float*)d_in[5];
    const float* W_hh1 = (const float*)d_in[6];
    const float* b_ih1 = (const float*)d_in[7];
    const float* b_hh1 = (const float*)d_in[8];
    const float* W_fc  = (const float*)d_in[9];
    const float* b_fc  = (const float*)d_in[10];
    float* out = (float*)d_out;

    dim3 grid(4096 / 16), block(NTH);
    hipLaunchKernelGGL(lstm2_mfma, grid, block, 0, stream,
                       x, W_ih0, W_hh0, b_ih0, b_hh0,
                       W_ih1, W_hh1, b_ih1, b_hh1, W_fc, b_fc, out);
}